// Round 7
// baseline (3472.361 us; speedup 1.0000x reference)
//
#include <hip/hip_runtime.h>
#include <math.h>

#define NXQ 729
#define M2Q 128
#define MQ  857
#define BQ  16
#define QPEN_ 0.1
#define SIGMA_ 0.1
#define NBLK 256

typedef double d4 __attribute__((ext_vector_type(4)));

// workspace offsets (in doubles)
constexpr int OFF_P    = 0;                        // 16x729
constexpr int OFF_H2   = OFF_P + BQ*NXQ;           // 128
constexpr int OFF_Z    = OFF_H2 + M2Q;             // 16x729
constexpr int OFF_S    = OFF_Z + BQ*NXQ;           // 16x857
constexpr int OFF_LAM  = OFF_S + BQ*MQ;            // 16x857
constexpr int OFF_D    = OFF_LAM + BQ*MQ;          // 16x857
constexpr int OFF_RP   = OFF_D + BQ*MQ;            // 16x857
constexpr int OFF_V    = OFF_RP + BQ*MQ;           // 16x857
constexpr int OFF_AINV = OFF_V + BQ*MQ;            // 16x729
constexpr int OFF_Y    = OFF_AINV + BQ*NXQ;        // 16x729
constexpr int OFF_GZ2  = OFF_Y + BQ*NXQ;           // 16x128
constexpr int OFF_Q2   = OFF_GZ2 + BQ*M2Q;         // 16x128
constexpr int OFF_USOL = OFF_Q2 + BQ*M2Q;          // 16x128
constexpr int OFF_G2B  = OFF_USOL + BQ*M2Q;        // 16x128
constexpr int OFF_TP   = OFF_G2B + BQ*M2Q;         // 12x16x128 t partials
constexpr int OFF_CMIN = OFF_TP + 12*BQ*M2Q;       // 13x16 alpha partial mins
constexpr int OFF_SG   = OFF_CMIN + 13*BQ + 48;    // 16x128x128 S matrices
constexpr int OFF_DZS  = OFF_SG;                   // 16x768 ALIASES SG prefix (phase-ordered safe)
constexpr int OFF_BARD = OFF_SG + BQ*M2Q*M2Q;      // grid barrier (uints), 8 dbl
constexpr int OFF_CNTD = OFF_BARD + 8;             // per-batch dz counters (uints)

// solve-phase LDS layout (doubles)
constexpr int L_SL   = 0;                  // 128 x 129 = 16512
constexpr int L_US   = 16512;              // 128
constexpr int L_INVD = 16640;              // 128
constexpr int L_RED2 = 16768;              // 256
constexpr int L_RED  = 17024;              // 8
constexpr int SMEM_DBL = 17032;
constexpr int SMEM_BYTES = SMEM_DBL * 8;   // 136256 B -> exactly 1 block/CU

__device__ __forceinline__ double wred_sum(double v) {
#pragma unroll
  for (int off = 32; off > 0; off >>= 1) v += __shfl_down(v, off, 64);
  return v;
}
__device__ __forceinline__ double wred_min(double v) {
#pragma unroll
  for (int off = 32; off > 0; off >>= 1) v = fmin(v, __shfl_down(v, off, 64));
  return v;
}
__device__ __forceinline__ double rsqrt64(double x) { return rsqrt(x); }

// grid barrier: relies on all NBLK blocks co-resident (1 block/CU by LDS size).
// acq/rel atomics + exit fence so peer writes are visible on every path.
__device__ __forceinline__ void gridbar(unsigned* bar) {
  __syncthreads();
  if (threadIdx.x == 0) {
    const unsigned gen = __hip_atomic_load(&bar[1], __ATOMIC_ACQUIRE, __HIP_MEMORY_SCOPE_AGENT);
    const unsigned arr = __hip_atomic_fetch_add(&bar[0], 1u, __ATOMIC_ACQ_REL, __HIP_MEMORY_SCOPE_AGENT);
    if (arr == (unsigned)(NBLK - 1)) {
      __hip_atomic_store(&bar[0], 0u, __ATOMIC_RELAXED, __HIP_MEMORY_SCOPE_AGENT);
      __hip_atomic_store(&bar[1], gen + 1u, __ATOMIC_RELEASE, __HIP_MEMORY_SCOPE_AGENT);
    } else {
      while (__hip_atomic_load(&bar[1], __ATOMIC_ACQUIRE, __HIP_MEMORY_SCOPE_AGENT) == gen)
        __builtin_amdgcn_s_sleep(2);
    }
    __threadfence();   // agent-scope acquire: invalidate stale cached peer data
  }
  __syncthreads();
}

// ---------------------------------------------------------------------------
// solve phase body (blocks 0..15, b = blk): factor K = S + D2inv, solve K u = t
// ---------------------------------------------------------------------------
__device__ __forceinline__ void solve_body(double* __restrict__ ws, double* __restrict__ sm,
                                           const int b) {
  const int tid = threadIdx.x, wave = tid >> 6, lane = tid & 63;
  double (*Sl)[129] = (double(*)[129])(sm + L_SL);
  double* us   = sm + L_US;
  double* invd = sm + L_INVD;
  double* red2 = sm + L_RED2;
  double* red  = sm + L_RED;
  double* s_   = ws + OFF_S   + b * MQ;
  double* lam_ = ws + OFF_LAM + b * MQ;
  double* Sgb  = ws + OFF_SG  + b * M2Q * M2Q;

  {
    const double2* __restrict__ Sg2 = (const double2*)Sgb;
    for (int idx = tid; idx < M2Q * M2Q / 2; idx += 256) {
      const double2 v = Sg2[idx];
      const int r = idx >> 6, c = (idx & 63) * 2;
      Sl[r][c] = v.x; Sl[r][c + 1] = v.y;
    }
  }
  if (tid < M2Q) {
    double t = 0.0;
#pragma unroll
    for (int c = 0; c < 12; ++c) t += ws[OFF_TP + (c * BQ + b) * M2Q + tid];
    us[tid] = t;
  }
  __syncthreads();
  if (tid < M2Q) Sl[tid][tid] += s_[NXQ + tid] / lam_[NXQ + tid];
  __syncthreads();

  // runtime probe of f64 MFMA C/D register->(row,col) mapping (verified R4)
  int rowm[4], colm[4];
  {
    const int rc = lane & 15, kq = lane >> 4;
    const double avr = (kq == 0) ? (double)rc : 0.0;
    const double bv1 = (kq == 0) ? 1.0 : 0.0;
    const double av1 = (kq == 0) ? 1.0 : 0.0;
    const double bvc = (kq == 0) ? (double)rc : 0.0;
    d4 zero = {0.0, 0.0, 0.0, 0.0};
    d4 dr = __builtin_amdgcn_mfma_f64_16x16x4f64(avr, bv1, zero, 0, 0, 0);
    d4 dc = __builtin_amdgcn_mfma_f64_16x16x4f64(av1, bvc, zero, 0, 0, 0);
#pragma unroll
    for (int e = 0; e < 4; ++e) { rowm[e] = (int)dr[e]; colm[e] = (int)dc[e]; }
  }

  // blocked Cholesky (NB=16) with forward substitution as extra TRSM row
  for (int kb = 0; kb < 8; ++kb) {
    const int K0 = kb * 16, J0 = K0 + 16, T = 128 - J0;
    if (wave == 0 && lane < 16) {
      const int r = lane;
      double a[16];
#pragma unroll
      for (int c = 0; c < 16; ++c) a[c] = Sl[K0 + r][K0 + c];
#pragma unroll
      for (int c = 0; c < 16; ++c) {
        const double dcc = __shfl(a[c], c, 64);
        const double rs = rsqrt64(dcc);
        a[c] *= rs;
        if (lane == c) invd[K0 + c] = rs;
#pragma unroll
        for (int k2 = c + 1; k2 < 16; ++k2) {
          const double lkc = __shfl(a[c], k2, 64);
          a[k2] = fma(-a[c], lkc, a[k2]);
        }
      }
#pragma unroll
      for (int c = 0; c < 16; ++c) Sl[K0 + r][K0 + c] = a[c];
    }
    __syncthreads();

    if (tid <= T) {
      const bool isU = (tid == T);
      double l[16];
      if (isU) {
#pragma unroll
        for (int c = 0; c < 16; ++c) l[c] = us[K0 + c];
      } else {
#pragma unroll
        for (int c = 0; c < 16; ++c) l[c] = Sl[J0 + tid][K0 + c];
      }
#pragma unroll
      for (int c = 0; c < 16; ++c) {
        const double lc = l[c] * invd[K0 + c];
        l[c] = lc;
#pragma unroll
        for (int k2 = c + 1; k2 < 16; ++k2)
          l[k2] = fma(-lc, Sl[K0 + k2][K0 + c], l[k2]);
      }
      if (isU) {
#pragma unroll
        for (int c = 0; c < 16; ++c) us[K0 + c] = l[c];
      } else {
#pragma unroll
        for (int c = 0; c < 16; ++c) Sl[J0 + tid][K0 + c] = l[c];
      }
    }
    __syncthreads();

    if (kb < 7) {
      if (tid < T) {
        double acc = 0.0;
#pragma unroll
        for (int c = 0; c < 16; ++c) acc = fma(Sl[J0 + tid][K0 + c], us[K0 + c], acc);
        us[J0 + tid] -= acc;
      }
      const int Tb = 7 - kb;
      const int rc = lane & 15, kq = lane >> 4;
      for (int idx = wave; idx < Tb * Tb; idx += 4) {
        const int i0 = J0 + (idx / Tb) * 16;
        const int j0 = J0 + (idx % Tb) * 16;
        d4 acc;
#pragma unroll
        for (int e = 0; e < 4; ++e) acc[e] = Sl[i0 + rowm[e]][j0 + colm[e]];
#pragma unroll
        for (int m = 0; m < 4; ++m) {
          const double av = -Sl[i0 + rc][K0 + 4 * m + kq];
          const double bv =  Sl[j0 + rc][K0 + 4 * m + kq];
          acc = __builtin_amdgcn_mfma_f64_16x16x4f64(av, bv, acc, 0, 0, 0);
        }
#pragma unroll
        for (int e = 0; e < 4; ++e) Sl[i0 + rowm[e]][j0 + colm[e]] = acc[e];
      }
    }
    __syncthreads();
  }

  // backward substitution L^T u = u'
  for (int kb = 7; kb >= 0; --kb) {
    const int K0 = kb * 16;
    if (kb < 7) {
      const int c = tid & 15, ch = tid >> 4;   // ch 0..15
      double part = 0.0;
      for (int k = K0 + 16 + ch; k < 128; k += 16) part = fma(Sl[k][K0 + c], us[k], part);
      red2[c * 16 + ch] = part;
      __syncthreads();
      if (tid < 16) {
        double acc = 0.0;
#pragma unroll
        for (int q = 0; q < 16; ++q) acc += red2[tid * 16 + q];
        us[K0 + tid] -= acc;
      }
      __syncthreads();
    }
    if (wave == 0 && lane < 16) {
      const int j = lane;
      double colv[16];
#pragma unroll
      for (int c = 0; c < 16; ++c) colv[c] = Sl[K0 + c][K0 + j];
      double x = us[K0 + j];
      const double iv = invd[K0 + j];
#pragma unroll
      for (int cc = 0; cc < 16; ++cc) {
        const int c = 15 - cc;
        const double xiv = x * iv;
        const double uc = __shfl(xiv, c, 64);
        if (j == c) x = xiv;
        else if (j < c) x = fma(-colv[c], uc, x);
      }
      us[K0 + j] = x;
    }
    __syncthreads();
  }

  // tail: write u, g2b = D2inv*u; m2-part ratio min -> cmin[12][b]
  double lmin = 1e300;
  if (tid < M2Q) {
    const double u = us[tid];
    ws[OFF_USOL + b * M2Q + tid] = u;
    const double g = (s_[NXQ + tid] / lam_[NXQ + tid]) * u;
    ws[OFF_G2B + b * M2Q + tid] = g;
    const int i = NXQ + tid;
    const double dsi = -ws[OFF_RP + b * MQ + i] - g;
    const double dlami = ws[OFF_V + b * MQ + i] + ws[OFF_D + b * MQ + i] * g;
    if (dsi < 0.0)   lmin = fmin(lmin, -s_[i] / dsi);
    if (dlami < 0.0) lmin = fmin(lmin, -lam_[i] / dlami);
  }
  if (tid < 128) {
    lmin = wred_min(lmin);
    if (lane == 0) red[wave] = lmin;
  }
  __syncthreads();
  if (tid == 0) ws[OFF_CMIN + 12 * BQ + b] = fmin(red[0], red[1]);
  __syncthreads();
}

// ---------------------------------------------------------------------------
// dz + fused update: chunk matvec; last-arriving block per batch does the update
// ---------------------------------------------------------------------------
__device__ __forceinline__ void dzupd_body(double* __restrict__ ws, double* __restrict__ sm,
                                           const float* __restrict__ G2, float* __restrict__ out,
                                           unsigned* __restrict__ cnt, const int chunk, const int b,
                                           const int last) {
  const int tid = threadIdx.x, lane = tid & 63, quad = tid >> 6;
  __shared__ int updflag;
  double* uvec = sm;          // 128
  double* part = sm + 128;    // 256
  const int c0 = chunk * 64;
  if (tid < M2Q) uvec[tid] = ws[OFF_USOL + b * M2Q + tid];
  __syncthreads();
  const int kk = tid & 63;
  const int k = c0 + kk;
  const int kg = (k < NXQ) ? k : (NXQ - 1);
  {
    const float* gp = G2 + (quad * 32) * NXQ + kg;
    double acc = 0.0;
#pragma unroll
    for (int j = 0; j < 32; ++j) acc = fma((double)gp[j * NXQ], uvec[quad * 32 + j], acc);
    part[quad * 64 + kk] = acc;
  }
  __syncthreads();
  double lmin = 1e300;
  if (tid < 64) {
    const int k2 = c0 + tid;
    if (k2 < NXQ) {
      const double w = part[tid] + part[64 + tid] + part[128 + tid] + part[192 + tid];
      const double dz = ws[OFF_Y + b * NXQ + k2] - ws[OFF_AINV + b * NXQ + k2] * w;
      ws[OFF_DZS + b * 768 + k2] = dz;
      const double dsi = dz - ws[OFF_RP + b * MQ + k2];
      const double dlami = ws[OFF_V + b * MQ + k2] - ws[OFF_D + b * MQ + k2] * dz;
      if (dsi < 0.0)   lmin = fmin(lmin, -ws[OFF_S + b * MQ + k2] / dsi);
      if (dlami < 0.0) lmin = fmin(lmin, -ws[OFF_LAM + b * MQ + k2] / dlami);
    }
    lmin = wred_min(lmin);
    if (tid == 0) ws[OFF_CMIN + chunk * BQ + b] = lmin;
  }
  __syncthreads();
  if (tid == 0) {
    __threadfence();
    const unsigned prev = __hip_atomic_fetch_add(&cnt[b], 1u, __ATOMIC_ACQ_REL, __HIP_MEMORY_SCOPE_AGENT);
    updflag = (prev == 11u) ? 1 : 0;
    if (updflag) __threadfence();   // acquire: other chunks' dzs/cmin now visible
  }
  __syncthreads();
  if (!updflag) return;

  // ---- inline update for batch b ----
  double* z    = ws + OFF_Z   + b * NXQ;
  double* s_   = ws + OFF_S   + b * MQ;
  double* lam_ = ws + OFF_LAM + b * MQ;
  double* dd   = ws + OFF_D   + b * MQ;
  double* rp   = ws + OFF_RP  + b * MQ;
  double* vv   = ws + OFF_V   + b * MQ;
  double* gz2  = ws + OFF_GZ2 + b * M2Q;
  if (tid == 0) {
    double m = 1e300;
#pragma unroll
    for (int c = 0; c < 13; ++c) m = fmin(m, ws[OFF_CMIN + c * BQ + b]);
    sm[1000] = fmin(1.0, 0.99 * m);
    __hip_atomic_store(&cnt[b], 0u, __ATOMIC_RELAXED, __HIP_MEMORY_SCOPE_AGENT);
  }
  __syncthreads();
  const double alpha = sm[1000];
  for (int i = tid; i < NXQ; i += 256) {
    const double dz = ws[OFF_DZS + b * 768 + i];
    s_[i]   += alpha * (dz - rp[i]);
    lam_[i] += alpha * (vv[i] - dd[i] * dz);
    const double zi = z[i] + alpha * dz;
    z[i] = zi;
    out[b * NXQ + i] = (float)zi;
  }
  if (tid < M2Q) {
    const int i = NXQ + tid;
    const double g = ws[OFF_G2B + b * M2Q + tid];
    s_[i]   += alpha * (-rp[i] - g);
    lam_[i] += alpha * (vv[i] + dd[i] * g);
    gz2[tid] += alpha * g;
  }
  __syncthreads();
  if (last) return;
  double musum = 0.0;
  for (int i = tid; i < MQ; i += 256) {
    const double si = s_[i], li = lam_[i];
    dd[i] = li / si;
    const double rpi = (i < NXQ) ? (si - z[i]) : (gz2[i - NXQ] + si - ws[OFF_H2 + i - NXQ]);
    rp[i] = rpi;
    musum += si * li;
  }
  musum = wred_sum(musum);
  if (lane == 0) sm[1004 + quad] = musum;
  __syncthreads();
  if (tid == 0) sm[1008] = SIGMA_ * ((sm[1004] + sm[1005] + sm[1006] + sm[1007]) / (double)MQ);
  __syncthreads();
  const double smu = sm[1008];
  for (int i = tid; i < MQ; i += 256) {
    const double si = s_[i], li = lam_[i];
    const double vi = smu / si - li + dd[i] * rp[i];
    vv[i] = vi;
    if (i >= NXQ) ws[OFF_Q2 + b * M2Q + (i - NXQ)] = li + vi;
    else ws[OFF_AINV + b * NXQ + i] = 1.0 / (QPEN_ + dd[i]);
  }
}

// ---------------------------------------------------------------------------
// prep: rhs/y chunk matvec + t partials (t[r] = G2[r,:].y, per-chunk)
// ---------------------------------------------------------------------------
__device__ __forceinline__ void prep_body(double* __restrict__ ws, double* __restrict__ sm,
                                          const float* __restrict__ G2, const int chunk, const int b) {
  const int tid = threadIdx.x, lane = tid & 63, quad = tid >> 6;
  double* uvec = sm;          // 128
  double* part = sm + 128;    // 256
  double* yl   = sm + 384;    // 64
  const int c0 = chunk * 64;
  if (tid < M2Q) uvec[tid] = ws[OFF_Q2 + b * M2Q + tid];
  __syncthreads();
  const int kk = tid & 63;
  const int k = c0 + kk;
  const int kg = (k < NXQ) ? k : (NXQ - 1);
  {
    const float* gp = G2 + (quad * 32) * NXQ + kg;
    double acc = 0.0;
#pragma unroll
    for (int j = 0; j < 32; ++j) acc = fma((double)gp[j * NXQ], uvec[quad * 32 + j], acc);
    part[quad * 64 + kk] = acc;
  }
  __syncthreads();
  if (tid < 64) {
    const int k2 = c0 + tid;
    double y = 0.0;
    if (k2 < NXQ) {
      const double w = part[tid] + part[64 + tid] + part[128 + tid] + part[192 + tid];
      const double rhsk = -(QPEN_ * ws[OFF_Z + b * NXQ + k2] + ws[OFF_P + b * NXQ + k2]
                            - ws[OFF_LAM + b * MQ + k2] - ws[OFF_V + b * MQ + k2] + w);
      y = ws[OFF_AINV + b * NXQ + k2] * rhsk;
      ws[OFF_Y + b * NXQ + k2] = y;
    }
    yl[tid] = y;
  }
  __syncthreads();
  // t partials: wave q handles rows q*32..q*32+31 (yl zero-padded for k>=NXQ)
  const double yv = yl[lane];
  for (int jr = 0; jr < 32; ++jr) {
    const int r = quad * 32 + jr;
    double v = (double)G2[r * NXQ + kg] * yv;
    v = wred_sum(v);
    if (lane == 0) ws[OFF_TP + (chunk * BQ + b) * M2Q + r] = v;
  }
  __syncthreads();
}

// ---------------------------------------------------------------------------
// sbuild: S_b tile = G2 * diag(ainv_b) * G2^T (32x32 tile), 256 thr / 4 waves
// ---------------------------------------------------------------------------
__device__ __forceinline__ void sbuild_body(double* __restrict__ ws, double* __restrict__ sm,
                                            const float* __restrict__ G2, const int tile, const int b) {
  const int tid = threadIdx.x, wave = tid >> 6, lane = tid & 63;
  const int R0 = (tile >> 2) * 32, C0 = (tile & 3) * 32;
  double* As = sm + wave * 2176;
  double* Bs = As + 1088;
  const double* __restrict__ ainv = ws + OFF_AINV + b * NXQ;
  const int k0w = wave * 183;
  const int kend = min(k0w + 183, NXQ);
  const int rg4 = (lane >> 3) * 4, cg4 = (lane & 7) * 4;
  double acc[4][4];
#pragma unroll
  for (int i = 0; i < 4; ++i)
#pragma unroll
    for (int j = 0; j < 4; ++j) acc[i][j] = 0.0;

  const int kk = lane & 31;
  for (int ch = 0; ch < 6; ++ch) {
    const int k = k0w + ch * 32 + kk;
    const bool ok = (k < kend);
    const double aik = ok ? ainv[k] : 0.0;
    __syncthreads();
#pragma unroll
    for (int it = 0; it < 16; ++it) {
      const int rr = (it << 1) | (lane >> 5);
      double av = 0.0, bv = 0.0;
      if (ok) {
        av = (double)G2[(R0 + rr) * NXQ + k] * aik;
        bv = (double)G2[(C0 + rr) * NXQ + k];
      }
      As[kk * 34 + rr] = av;
      Bs[kk * 34 + rr] = bv;
    }
    __syncthreads();
#pragma unroll 8
    for (int q = 0; q < 32; ++q) {
      const double a0 = As[q*34 + rg4 + 0], a1 = As[q*34 + rg4 + 1],
                   a2 = As[q*34 + rg4 + 2], a3 = As[q*34 + rg4 + 3];
      const double b0 = Bs[q*34 + cg4 + 0], b1 = Bs[q*34 + cg4 + 1],
                   b2 = Bs[q*34 + cg4 + 2], b3 = Bs[q*34 + cg4 + 3];
      acc[0][0] += a0*b0; acc[0][1] += a0*b1; acc[0][2] += a0*b2; acc[0][3] += a0*b3;
      acc[1][0] += a1*b0; acc[1][1] += a1*b1; acc[1][2] += a1*b2; acc[1][3] += a1*b3;
      acc[2][0] += a2*b0; acc[2][1] += a2*b1; acc[2][2] += a2*b2; acc[2][3] += a2*b3;
      acc[3][0] += a3*b0; acc[3][1] += a3*b1; acc[3][2] += a3*b2; acc[3][3] += a3*b3;
    }
  }
  __syncthreads();
#pragma unroll
  for (int i = 0; i < 4; ++i)
#pragma unroll
    for (int j = 0; j < 4; ++j)
      As[(rg4 + i) * 32 + cg4 + j] = acc[i][j];
  __syncthreads();
  double* __restrict__ Sgb = ws + OFF_SG + b * (M2Q * M2Q);
  for (int idx = tid; idx < 1024; idx += 256) {
    const double v = sm[idx] + sm[2176 + idx] + sm[4352 + idx] + sm[6528 + idx];
    Sgb[(R0 + (idx >> 5)) * M2Q + C0 + (idx & 31)] = v;
  }
  __syncthreads();
}

// ---------------------------------------------------------------------------
// persistent kernel: all phases, grid barriers between
// ---------------------------------------------------------------------------
__global__ __launch_bounds__(256, 1)
void persist_kernel(const float* __restrict__ puzzles, const float* __restrict__ G2,
                    const float* __restrict__ z2in, const float* __restrict__ s2in,
                    double* __restrict__ ws, float* __restrict__ out) {
  const int blk = blockIdx.x;
  const int tid = threadIdx.x, wave = tid >> 6, lane = tid & 63;
  extern __shared__ double sm[];
  unsigned* bar = (unsigned*)(ws + OFF_BARD);
  unsigned* cnt = (unsigned*)(ws + OFF_CNTD);
  const int tile = blk >> 4, b = blk & 15;

  // ---------- INIT ----------
  if (blk < BQ) {
    const int bb = blk;
    for (int i = tid; i < NXQ; i += 256) {
      ws[OFF_P + bb * NXQ + i] = -(double)puzzles[bb * NXQ + i];
      ws[OFF_Z + bb * NXQ + i] = 0.0;
      ws[OFF_AINV + bb * NXQ + i] = 1.0 / (QPEN_ + 1.0);
      ws[OFF_RP + bb * MQ + i] = 1.0;       // s - z = 1
      ws[OFF_V + bb * MQ + i] = SIGMA_;     // 0.1 - 1 + 1
    }
    for (int i = tid; i < MQ; i += 256) {
      ws[OFF_S + bb * MQ + i] = 1.0;
      ws[OFF_LAM + bb * MQ + i] = 1.0;
      ws[OFF_D + bb * MQ + i] = 1.0;
    }
    if (tid < M2Q) ws[OFF_GZ2 + bb * M2Q + tid] = 0.0;
    if (tid == 0) __hip_atomic_store(&cnt[bb], 0u, __ATOMIC_RELAXED, __HIP_MEMORY_SCOPE_AGENT);
  } else if (blk < 16 + M2Q) {
    const int r = blk - 16;
    double acc = 0.0;
    for (int kx = tid; kx < NXQ; kx += 256)
      acc += (double)G2[r * NXQ + kx] * (double)z2in[kx];
    acc = wred_sum(acc);
    if (lane == 0) sm[wave] = acc;
    __syncthreads();
    if (tid == 0) {
      const double h2r = sm[0] + sm[1] + sm[2] + sm[3] + (double)s2in[r];
      ws[OFF_H2 + r] = h2r;
      sm[4] = h2r;
    }
    __syncthreads();
    if (tid < BQ) {
      const double rp2 = 1.0 - sm[4];          // gz2(0) + s(1) - h2
      ws[OFF_RP + tid * MQ + NXQ + r] = rp2;
      ws[OFF_V  + tid * MQ + NXQ + r] = rp2 - 0.9;   // 0.1 - 1 + rp2
      ws[OFF_Q2 + tid * M2Q + r] = rp2 + 0.1;        // lam + v
    }
  }
  gridbar(bar);

  // ---------- pre-loop PREP + SBUILD ----------
  if (tile < 12) prep_body(ws, sm, G2, tile, b);
  sbuild_body(ws, sm, G2, tile, b);
  gridbar(bar);

  // ---------- main loop ----------
  for (int it = 0; it < 10; ++it) {
    if (blk < BQ) solve_body(ws, sm, blk);
    gridbar(bar);
    if (tile < 12) dzupd_body(ws, sm, G2, out, cnt, tile, b, (it == 9) ? 1 : 0);
    if (it < 9) {
      gridbar(bar);
      if (tile < 12) prep_body(ws, sm, G2, tile, b);
      sbuild_body(ws, sm, G2, tile, b);
      gridbar(bar);
    }
  }
}

extern "C" void kernel_launch(void* const* d_in, const int* in_sizes, int n_in,
                              void* d_out, int out_size, void* d_ws, size_t ws_size,
                              hipStream_t stream) {
  const float* puzzles = (const float*)d_in[0];
  const float* G2      = (const float*)d_in[1];
  const float* z2      = (const float*)d_in[2];
  const float* s2      = (const float*)d_in[3];
  float* out = (float*)d_out;
  double* ws = (double*)d_ws;

  (void)hipFuncSetAttribute(reinterpret_cast<const void*>(&persist_kernel),
                            hipFuncAttributeMaxDynamicSharedMemorySize, SMEM_BYTES);
  // zero the grid-barrier state (ws is poisoned 0xAA before each timed launch)
  (void)hipMemsetAsync((char*)d_ws + (size_t)OFF_BARD * 8, 0, 64, stream);

  // regular launch: 136 KB LDS/block -> exactly 1 block/CU, grid == 256 CUs,
  // so all blocks are co-resident and the hand-rolled grid barrier is safe.
  persist_kernel<<<dim3(NBLK), dim3(256), SMEM_BYTES, stream>>>(puzzles, G2, z2, s2, ws, out);
}

// Round 8
// 2512.073 us; speedup vs baseline: 1.3823x; 1.3823x over previous
//
#include <hip/hip_runtime.h>
#include <math.h>

#define NXQ 729
#define M2Q 128
#define MQ  857
#define BQ  16
#define QPEN_ 0.1
#define SIGMA_ 0.1
#define NBLK 256
#define NTHR 1024

typedef double d4 __attribute__((ext_vector_type(4)));

// workspace offsets (in doubles)
constexpr int OFF_P    = 0;                        // 16x729
constexpr int OFF_H2   = OFF_P + BQ*NXQ;           // 128
constexpr int OFF_Z    = OFF_H2 + M2Q;             // 16x729
constexpr int OFF_S    = OFF_Z + BQ*NXQ;           // 16x857
constexpr int OFF_LAM  = OFF_S + BQ*MQ;            // 16x857
constexpr int OFF_D    = OFF_LAM + BQ*MQ;          // 16x857
constexpr int OFF_RP   = OFF_D + BQ*MQ;            // 16x857
constexpr int OFF_V    = OFF_RP + BQ*MQ;           // 16x857
constexpr int OFF_AINV = OFF_V + BQ*MQ;            // 16x729
constexpr int OFF_Y    = OFF_AINV + BQ*NXQ;        // 16x729
constexpr int OFF_GZ2  = OFF_Y + BQ*NXQ;           // 16x128
constexpr int OFF_Q2   = OFF_GZ2 + BQ*M2Q;         // 16x128
constexpr int OFF_USOL = OFF_Q2 + BQ*M2Q;          // 16x128
constexpr int OFF_G2B  = OFF_USOL + BQ*M2Q;        // 16x128
constexpr int OFF_TP   = OFF_G2B + BQ*M2Q;         // 12x16x128 t partials
constexpr int OFF_CMIN = OFF_TP + 12*BQ*M2Q;       // 13x16 alpha partial mins
constexpr int OFF_SG   = OFF_CMIN + 13*BQ + 48;    // 16x128x128 S matrices
constexpr int OFF_DZS  = OFF_SG;                   // 16x768 ALIASES SG prefix (phase-ordered safe)
constexpr int OFF_BARD = OFF_SG + BQ*M2Q*M2Q;      // barrier + counters (uints), 160 dbl
// uint layout inside BARD: root@[0], gen@[16], grp[g]@[32+16g] g<16, cnt[b]@[288+b]

// solve-phase LDS layout (doubles)
constexpr int L_SL   = 0;                  // 128 x 129 = 16512
constexpr int L_US   = 16512;              // 128
constexpr int L_INVD = 16640;              // 128
constexpr int L_RED2 = 16768;              // 1024
constexpr int L_RED  = 17792;              // 32
constexpr int SMEM_DBL = 17824;
constexpr int SMEM_BYTES = SMEM_DBL * 8;   // 142592 B -> exactly 1 block/CU

__device__ __forceinline__ double wred_sum(double v) {
#pragma unroll
  for (int off = 32; off > 0; off >>= 1) v += __shfl_down(v, off, 64);
  return v;
}
__device__ __forceinline__ double wred_min(double v) {
#pragma unroll
  for (int off = 32; off > 0; off >>= 1) v = fmin(v, __shfl_down(v, off, 64));
  return v;
}
__device__ __forceinline__ double rsqrt64(double x) { return rsqrt(x); }

// hierarchical grid barrier: 16 groups of 16 blocks; per-group counter and the
// generation flag live on separate cache lines; polling is RELAXED + s_sleep.
__device__ __forceinline__ void gridbar(unsigned* bs) {
  __syncthreads();
  if (threadIdx.x == 0) {
    unsigned* root = bs;
    unsigned* gen  = bs + 16;
    unsigned* grp  = bs + 32 + (blockIdx.x >> 4) * 16;
    const unsigned myGen = __hip_atomic_load(gen, __ATOMIC_RELAXED, __HIP_MEMORY_SCOPE_AGENT);
    __threadfence();   // release: make prior writes device-visible before arrival
    const unsigned p = __hip_atomic_fetch_add(grp, 1u, __ATOMIC_RELAXED, __HIP_MEMORY_SCOPE_AGENT);
    if (p == 15u) {
      __hip_atomic_store(grp, 0u, __ATOMIC_RELAXED, __HIP_MEMORY_SCOPE_AGENT);
      const unsigned rp = __hip_atomic_fetch_add(root, 1u, __ATOMIC_RELAXED, __HIP_MEMORY_SCOPE_AGENT);
      if (rp == 15u) {
        __hip_atomic_store(root, 0u, __ATOMIC_RELAXED, __HIP_MEMORY_SCOPE_AGENT);
        __hip_atomic_store(gen, myGen + 1u, __ATOMIC_RELEASE, __HIP_MEMORY_SCOPE_AGENT);
      }
    }
    while (__hip_atomic_load(gen, __ATOMIC_RELAXED, __HIP_MEMORY_SCOPE_AGENT) == myGen)
      __builtin_amdgcn_s_sleep(8);
    __threadfence();   // acquire: invalidate stale cached peer data
  }
  __syncthreads();
}

// ---------------------------------------------------------------------------
// solve phase body (blocks 0..15): factor K = S + D2inv, solve K u = t. 1024 thr.
// ---------------------------------------------------------------------------
__device__ __forceinline__ void solve_body(double* __restrict__ ws, double* __restrict__ sm,
                                           const int b) {
  const int tid = threadIdx.x, wave = tid >> 6, lane = tid & 63;
  double (*Sl)[129] = (double(*)[129])(sm + L_SL);
  double* us   = sm + L_US;
  double* invd = sm + L_INVD;
  double* red2 = sm + L_RED2;
  double* red  = sm + L_RED;
  double* s_   = ws + OFF_S   + b * MQ;
  double* lam_ = ws + OFF_LAM + b * MQ;
  double* Sgb  = ws + OFF_SG  + b * M2Q * M2Q;

  {
    const double2* __restrict__ Sg2 = (const double2*)Sgb;
    for (int idx = tid; idx < M2Q * M2Q / 2; idx += NTHR) {
      const double2 v = Sg2[idx];
      const int r = idx >> 6, c = (idx & 63) * 2;
      Sl[r][c] = v.x; Sl[r][c + 1] = v.y;
    }
  }
  if (tid < M2Q) {
    double t = 0.0;
#pragma unroll
    for (int c = 0; c < 12; ++c) t += ws[OFF_TP + (c * BQ + b) * M2Q + tid];
    us[tid] = t;
  }
  __syncthreads();
  if (tid < M2Q) Sl[tid][tid] += s_[NXQ + tid] / lam_[NXQ + tid];
  __syncthreads();

  // runtime probe of f64 MFMA C/D register->(row,col) mapping (verified R4)
  int rowm[4], colm[4];
  {
    const int rc = lane & 15, kq = lane >> 4;
    const double avr = (kq == 0) ? (double)rc : 0.0;
    const double bv1 = (kq == 0) ? 1.0 : 0.0;
    const double av1 = (kq == 0) ? 1.0 : 0.0;
    const double bvc = (kq == 0) ? (double)rc : 0.0;
    d4 zero = {0.0, 0.0, 0.0, 0.0};
    d4 dr = __builtin_amdgcn_mfma_f64_16x16x4f64(avr, bv1, zero, 0, 0, 0);
    d4 dc = __builtin_amdgcn_mfma_f64_16x16x4f64(av1, bvc, zero, 0, 0, 0);
#pragma unroll
    for (int e = 0; e < 4; ++e) { rowm[e] = (int)dr[e]; colm[e] = (int)dc[e]; }
  }

  // blocked Cholesky (NB=16) with forward substitution as extra TRSM row
  for (int kb = 0; kb < 8; ++kb) {
    const int K0 = kb * 16, J0 = K0 + 16, T = 128 - J0;
    if (wave == 0 && lane < 16) {
      const int r = lane;
      double a[16];
#pragma unroll
      for (int c = 0; c < 16; ++c) a[c] = Sl[K0 + r][K0 + c];
#pragma unroll
      for (int c = 0; c < 16; ++c) {
        const double dcc = __shfl(a[c], c, 64);
        const double rs = rsqrt64(dcc);
        a[c] *= rs;
        if (lane == c) invd[K0 + c] = rs;
#pragma unroll
        for (int k2 = c + 1; k2 < 16; ++k2) {
          const double lkc = __shfl(a[c], k2, 64);
          a[k2] = fma(-a[c], lkc, a[k2]);
        }
      }
#pragma unroll
      for (int c = 0; c < 16; ++c) Sl[K0 + r][K0 + c] = a[c];
    }
    __syncthreads();

    if (tid <= T) {
      const bool isU = (tid == T);
      double l[16];
      if (isU) {
#pragma unroll
        for (int c = 0; c < 16; ++c) l[c] = us[K0 + c];
      } else {
#pragma unroll
        for (int c = 0; c < 16; ++c) l[c] = Sl[J0 + tid][K0 + c];
      }
#pragma unroll
      for (int c = 0; c < 16; ++c) {
        const double lc = l[c] * invd[K0 + c];
        l[c] = lc;
#pragma unroll
        for (int k2 = c + 1; k2 < 16; ++k2)
          l[k2] = fma(-lc, Sl[K0 + k2][K0 + c], l[k2]);
      }
      if (isU) {
#pragma unroll
        for (int c = 0; c < 16; ++c) us[K0 + c] = l[c];
      } else {
#pragma unroll
        for (int c = 0; c < 16; ++c) Sl[J0 + tid][K0 + c] = l[c];
      }
    }
    __syncthreads();

    if (kb < 7) {
      if (tid < T) {
        double acc = 0.0;
#pragma unroll
        for (int c = 0; c < 16; ++c) acc = fma(Sl[J0 + tid][K0 + c], us[K0 + c], acc);
        us[J0 + tid] -= acc;
      }
      const int Tb = 7 - kb;
      const int rc = lane & 15, kq = lane >> 4;
      for (int idx = wave; idx < Tb * Tb; idx += 16) {
        const int i0 = J0 + (idx / Tb) * 16;
        const int j0 = J0 + (idx % Tb) * 16;
        d4 acc;
#pragma unroll
        for (int e = 0; e < 4; ++e) acc[e] = Sl[i0 + rowm[e]][j0 + colm[e]];
#pragma unroll
        for (int m = 0; m < 4; ++m) {
          const double av = -Sl[i0 + rc][K0 + 4 * m + kq];
          const double bv =  Sl[j0 + rc][K0 + 4 * m + kq];
          acc = __builtin_amdgcn_mfma_f64_16x16x4f64(av, bv, acc, 0, 0, 0);
        }
#pragma unroll
        for (int e = 0; e < 4; ++e) Sl[i0 + rowm[e]][j0 + colm[e]] = acc[e];
      }
    }
    __syncthreads();
  }

  // backward substitution L^T u = u'
  for (int kb = 7; kb >= 0; --kb) {
    const int K0 = kb * 16;
    if (kb < 7) {
      const int c = tid & 15, ch = tid >> 4;   // ch 0..63
      double part = 0.0;
      for (int k = K0 + 16 + ch; k < 128; k += 64) part = fma(Sl[k][K0 + c], us[k], part);
      red2[c * 64 + ch] = part;
      __syncthreads();
      if (tid < 16) {
        double acc = 0.0;
#pragma unroll
        for (int q = 0; q < 64; ++q) acc += red2[tid * 64 + q];
        us[K0 + tid] -= acc;
      }
      __syncthreads();
    }
    if (wave == 0 && lane < 16) {
      const int j = lane;
      double colv[16];
#pragma unroll
      for (int c = 0; c < 16; ++c) colv[c] = Sl[K0 + c][K0 + j];
      double x = us[K0 + j];
      const double iv = invd[K0 + j];
#pragma unroll
      for (int cc = 0; cc < 16; ++cc) {
        const int c = 15 - cc;
        const double xiv = x * iv;
        const double uc = __shfl(xiv, c, 64);
        if (j == c) x = xiv;
        else if (j < c) x = fma(-colv[c], uc, x);
      }
      us[K0 + j] = x;
    }
    __syncthreads();
  }

  // tail: write u, g2b = D2inv*u; m2-part ratio min -> cmin[12][b]
  double lmin = 1e300;
  if (tid < M2Q) {
    const double u = us[tid];
    ws[OFF_USOL + b * M2Q + tid] = u;
    const double g = (s_[NXQ + tid] / lam_[NXQ + tid]) * u;
    ws[OFF_G2B + b * M2Q + tid] = g;
    const int i = NXQ + tid;
    const double dsi = -ws[OFF_RP + b * MQ + i] - g;
    const double dlami = ws[OFF_V + b * MQ + i] + ws[OFF_D + b * MQ + i] * g;
    if (dsi < 0.0)   lmin = fmin(lmin, -s_[i] / dsi);
    if (dlami < 0.0) lmin = fmin(lmin, -lam_[i] / dlami);
  }
  if (tid < 128) {
    lmin = wred_min(lmin);
    if (lane == 0) red[wave] = lmin;
  }
  __syncthreads();
  if (tid == 0) ws[OFF_CMIN + 12 * BQ + b] = fmin(red[0], red[1]);
  __syncthreads();
}

// ---------------------------------------------------------------------------
// dz + fused update (blocks with tile<12): chunk matvec; 12th arriver updates.
// 1024 thr: seg = tid>>6 (16 row-segments of 8 rows), kk = tid&63.
// ---------------------------------------------------------------------------
__device__ __forceinline__ void dzupd_body(double* __restrict__ ws, double* __restrict__ sm,
                                           const float* __restrict__ G2, float* __restrict__ out,
                                           unsigned* __restrict__ cnt, const int chunk, const int b,
                                           const int last) {
  const int tid = threadIdx.x, lane = tid & 63, seg = tid >> 6;
  __shared__ int updflag;
  double* uvec = sm;            // 128
  double* part = sm + 128;      // 1024
  const int c0 = chunk * 64;
  if (tid < M2Q) uvec[tid] = ws[OFF_USOL + b * M2Q + tid];
  __syncthreads();
  const int kk = lane;
  const int k = c0 + kk;
  const int kg = (k < NXQ) ? k : (NXQ - 1);
  {
    const float* gp = G2 + (seg * 8) * NXQ + kg;
    double acc = 0.0;
#pragma unroll
    for (int j = 0; j < 8; ++j) acc = fma((double)gp[j * NXQ], uvec[seg * 8 + j], acc);
    part[seg * 64 + kk] = acc;
  }
  __syncthreads();
  double lmin = 1e300;
  if (tid < 64) {
    const int k2 = c0 + tid;
    if (k2 < NXQ) {
      double w = 0.0;
#pragma unroll
      for (int q = 0; q < 16; ++q) w += part[q * 64 + tid];
      const double dz = ws[OFF_Y + b * NXQ + k2] - ws[OFF_AINV + b * NXQ + k2] * w;
      ws[OFF_DZS + b * 768 + k2] = dz;
      const double dsi = dz - ws[OFF_RP + b * MQ + k2];
      const double dlami = ws[OFF_V + b * MQ + k2] - ws[OFF_D + b * MQ + k2] * dz;
      if (dsi < 0.0)   lmin = fmin(lmin, -ws[OFF_S + b * MQ + k2] / dsi);
      if (dlami < 0.0) lmin = fmin(lmin, -ws[OFF_LAM + b * MQ + k2] / dlami);
    }
    lmin = wred_min(lmin);
    if (tid == 0) ws[OFF_CMIN + chunk * BQ + b] = lmin;
  }
  __syncthreads();
  if (tid == 0) {
    __threadfence();
    const unsigned prev = __hip_atomic_fetch_add(&cnt[b], 1u, __ATOMIC_ACQ_REL, __HIP_MEMORY_SCOPE_AGENT);
    updflag = (prev == 11u) ? 1 : 0;
    if (updflag) __threadfence();   // acquire: other chunks' dzs/cmin now visible
  }
  __syncthreads();
  if (!updflag) return;

  // ---- inline update for batch b ----
  double* z    = ws + OFF_Z   + b * NXQ;
  double* s_   = ws + OFF_S   + b * MQ;
  double* lam_ = ws + OFF_LAM + b * MQ;
  double* dd   = ws + OFF_D   + b * MQ;
  double* rp   = ws + OFF_RP  + b * MQ;
  double* vv   = ws + OFF_V   + b * MQ;
  double* gz2  = ws + OFF_GZ2 + b * M2Q;
  if (tid == 0) {
    double m = 1e300;
#pragma unroll
    for (int c = 0; c < 13; ++c) m = fmin(m, ws[OFF_CMIN + c * BQ + b]);
    sm[1296] = fmin(1.0, 0.99 * m);
    __hip_atomic_store(&cnt[b], 0u, __ATOMIC_RELAXED, __HIP_MEMORY_SCOPE_AGENT);
  }
  __syncthreads();
  const double alpha = sm[1296];
  for (int i = tid; i < NXQ; i += NTHR) {
    const double dz = ws[OFF_DZS + b * 768 + i];
    s_[i]   += alpha * (dz - rp[i]);
    lam_[i] += alpha * (vv[i] - dd[i] * dz);
    const double zi = z[i] + alpha * dz;
    z[i] = zi;
    out[b * NXQ + i] = (float)zi;
  }
  if (tid < M2Q) {
    const int i = NXQ + tid;
    const double g = ws[OFF_G2B + b * M2Q + tid];
    s_[i]   += alpha * (-rp[i] - g);
    lam_[i] += alpha * (vv[i] + dd[i] * g);
    gz2[tid] += alpha * g;
  }
  __syncthreads();
  if (last) return;
  double musum = 0.0;
  for (int i = tid; i < MQ; i += NTHR) {
    const double si = s_[i], li = lam_[i];
    dd[i] = li / si;
    const double rpi = (i < NXQ) ? (si - z[i]) : (gz2[i - NXQ] + si - ws[OFF_H2 + i - NXQ]);
    rp[i] = rpi;
    musum += si * li;
  }
  musum = wred_sum(musum);
  if (lane == 0) sm[1280 + seg] = musum;
  __syncthreads();
  if (tid == 0) {
    double t = 0.0;
#pragma unroll
    for (int w = 0; w < 16; ++w) t += sm[1280 + w];
    sm[1297] = SIGMA_ * (t / (double)MQ);
  }
  __syncthreads();
  const double smu = sm[1297];
  for (int i = tid; i < MQ; i += NTHR) {
    const double si = s_[i], li = lam_[i];
    const double vi = smu / si - li + dd[i] * rp[i];
    vv[i] = vi;
    if (i >= NXQ) ws[OFF_Q2 + b * M2Q + (i - NXQ)] = li + vi;
    else ws[OFF_AINV + b * NXQ + i] = 1.0 / (QPEN_ + dd[i]);
  }
}

// ---------------------------------------------------------------------------
// prep (blocks with tile<12): rhs/y chunk matvec + t partials
// ---------------------------------------------------------------------------
__device__ __forceinline__ void prep_body(double* __restrict__ ws, double* __restrict__ sm,
                                          const float* __restrict__ G2, const int chunk, const int b) {
  const int tid = threadIdx.x, lane = tid & 63, seg = tid >> 6;
  double* uvec = sm;            // 128
  double* part = sm + 128;      // 1024
  double* yl   = sm + 1152;     // 64
  const int c0 = chunk * 64;
  if (tid < M2Q) uvec[tid] = ws[OFF_Q2 + b * M2Q + tid];
  __syncthreads();
  const int kk = lane;
  const int k = c0 + kk;
  const int kg = (k < NXQ) ? k : (NXQ - 1);
  {
    const float* gp = G2 + (seg * 8) * NXQ + kg;
    double acc = 0.0;
#pragma unroll
    for (int j = 0; j < 8; ++j) acc = fma((double)gp[j * NXQ], uvec[seg * 8 + j], acc);
    part[seg * 64 + kk] = acc;
  }
  __syncthreads();
  if (tid < 64) {
    const int k2 = c0 + tid;
    double y = 0.0;
    if (k2 < NXQ) {
      double w = 0.0;
#pragma unroll
      for (int q = 0; q < 16; ++q) w += part[q * 64 + tid];
      const double rhsk = -(QPEN_ * ws[OFF_Z + b * NXQ + k2] + ws[OFF_P + b * NXQ + k2]
                            - ws[OFF_LAM + b * MQ + k2] - ws[OFF_V + b * MQ + k2] + w);
      y = ws[OFF_AINV + b * NXQ + k2] * rhsk;
      ws[OFF_Y + b * NXQ + k2] = y;
    }
    yl[tid] = y;
  }
  __syncthreads();
  // t partials: wave seg handles rows seg*8..seg*8+7 (yl zero-padded for k>=NXQ)
  const double yv = yl[lane];
#pragma unroll
  for (int jr = 0; jr < 8; ++jr) {
    const int r = seg * 8 + jr;
    double v = (double)G2[r * NXQ + kg] * yv;
    v = wred_sum(v);
    if (lane == 0) ws[OFF_TP + (chunk * BQ + b) * M2Q + r] = v;
  }
  __syncthreads();
}

// ---------------------------------------------------------------------------
// sbuild (all blocks): S_b 32x32 tile = G2 * diag(ainv_b) * G2^T.
// LDS-throughput-bound 4-wave core; waves 4..15 only help the epilogue.
// ---------------------------------------------------------------------------
__device__ __forceinline__ void sbuild_body(double* __restrict__ ws, double* __restrict__ sm,
                                            const float* __restrict__ G2, const int tile, const int b) {
  const int tid = threadIdx.x, wave = tid >> 6, lane = tid & 63;
  const int R0 = (tile >> 2) * 32, C0 = (tile & 3) * 32;
  double* As = sm + wave * 2176;
  double* Bs = As + 1088;
  const double* __restrict__ ainv = ws + OFF_AINV + b * NXQ;
  const int k0w = wave * 183;
  const int kend = min(k0w + 183, NXQ);
  const int rg4 = (lane >> 3) * 4, cg4 = (lane & 7) * 4;
  double acc[4][4];
#pragma unroll
  for (int i = 0; i < 4; ++i)
#pragma unroll
    for (int j = 0; j < 4; ++j) acc[i][j] = 0.0;

  const int kk = lane & 31;
  for (int ch = 0; ch < 6; ++ch) {
    __syncthreads();
    if (wave < 4) {
      const int k = k0w + ch * 32 + kk;
      const bool ok = (k < kend);
      const double aik = ok ? ainv[k] : 0.0;
#pragma unroll
      for (int it = 0; it < 16; ++it) {
        const int rr = (it << 1) | (lane >> 5);
        double av = 0.0, bv = 0.0;
        if (ok) {
          av = (double)G2[(R0 + rr) * NXQ + k] * aik;
          bv = (double)G2[(C0 + rr) * NXQ + k];
        }
        As[kk * 34 + rr] = av;
        Bs[kk * 34 + rr] = bv;
      }
    }
    __syncthreads();
    if (wave < 4) {
#pragma unroll 8
      for (int q = 0; q < 32; ++q) {
        const double a0 = As[q*34 + rg4 + 0], a1 = As[q*34 + rg4 + 1],
                     a2 = As[q*34 + rg4 + 2], a3 = As[q*34 + rg4 + 3];
        const double b0 = Bs[q*34 + cg4 + 0], b1 = Bs[q*34 + cg4 + 1],
                     b2 = Bs[q*34 + cg4 + 2], b3 = Bs[q*34 + cg4 + 3];
        acc[0][0] += a0*b0; acc[0][1] += a0*b1; acc[0][2] += a0*b2; acc[0][3] += a0*b3;
        acc[1][0] += a1*b0; acc[1][1] += a1*b1; acc[1][2] += a1*b2; acc[1][3] += a1*b3;
        acc[2][0] += a2*b0; acc[2][1] += a2*b1; acc[2][2] += a2*b2; acc[2][3] += a2*b3;
        acc[3][0] += a3*b0; acc[3][1] += a3*b1; acc[3][2] += a3*b2; acc[3][3] += a3*b3;
      }
    }
  }
  __syncthreads();
  if (wave < 4) {
#pragma unroll
    for (int i = 0; i < 4; ++i)
#pragma unroll
      for (int j = 0; j < 4; ++j)
        As[(rg4 + i) * 32 + cg4 + j] = acc[i][j];
  }
  __syncthreads();
  double* __restrict__ Sgb = ws + OFF_SG + b * (M2Q * M2Q);
  if (tid < 1024) {
    const int idx = tid;
    const double v = sm[idx] + sm[2176 + idx] + sm[4352 + idx] + sm[6528 + idx];
    Sgb[(R0 + (idx >> 5)) * M2Q + C0 + (idx & 31)] = v;
  }
  __syncthreads();
}

// ---------------------------------------------------------------------------
// persistent kernel: all phases, hierarchical grid barriers between
// ---------------------------------------------------------------------------
__global__ __launch_bounds__(NTHR, 1)
void persist_kernel(const float* __restrict__ puzzles, const float* __restrict__ G2,
                    const float* __restrict__ z2in, const float* __restrict__ s2in,
                    double* __restrict__ ws, float* __restrict__ out) {
  const int blk = blockIdx.x;
  const int tid = threadIdx.x, wave = tid >> 6, lane = tid & 63;
  extern __shared__ double sm[];
  unsigned* bs  = (unsigned*)(ws + OFF_BARD);
  unsigned* cnt = bs + 288;
  const int tile = blk >> 4, b = blk & 15;

  // ---------- INIT ----------
  if (blk < BQ) {
    const int bb = blk;
    for (int i = tid; i < NXQ; i += NTHR) {
      ws[OFF_P + bb * NXQ + i] = -(double)puzzles[bb * NXQ + i];
      ws[OFF_Z + bb * NXQ + i] = 0.0;
      ws[OFF_AINV + bb * NXQ + i] = 1.0 / (QPEN_ + 1.0);
      ws[OFF_RP + bb * MQ + i] = 1.0;       // s - z = 1
      ws[OFF_V + bb * MQ + i] = SIGMA_;     // 0.1 - 1 + 1
    }
    for (int i = tid; i < MQ; i += NTHR) {
      ws[OFF_S + bb * MQ + i] = 1.0;
      ws[OFF_LAM + bb * MQ + i] = 1.0;
      ws[OFF_D + bb * MQ + i] = 1.0;
    }
    if (tid < M2Q) ws[OFF_GZ2 + bb * M2Q + tid] = 0.0;
  } else if (blk < 16 + M2Q) {
    const int r = blk - 16;
    double acc = 0.0;
    for (int kx = tid; kx < NXQ; kx += NTHR)
      acc += (double)G2[r * NXQ + kx] * (double)z2in[kx];
    acc = wred_sum(acc);
    if (lane == 0) sm[wave] = acc;
    __syncthreads();
    if (tid == 0) {
      double t = 0.0;
#pragma unroll
      for (int w = 0; w < 16; ++w) t += sm[w];
      const double h2r = t + (double)s2in[r];
      ws[OFF_H2 + r] = h2r;
      sm[20] = h2r;
    }
    __syncthreads();
    if (tid < BQ) {
      const double rp2 = 1.0 - sm[20];         // gz2(0) + s(1) - h2
      ws[OFF_RP + tid * MQ + NXQ + r] = rp2;
      ws[OFF_V  + tid * MQ + NXQ + r] = rp2 - 0.9;   // 0.1 - 1 + rp2
      ws[OFF_Q2 + tid * M2Q + r] = rp2 + 0.1;        // lam + v
    }
  }
  gridbar(bs);

  // ---------- pre-loop PREP + SBUILD ----------
  if (tile < 12) prep_body(ws, sm, G2, tile, b);
  sbuild_body(ws, sm, G2, tile, b);
  gridbar(bs);

  // ---------- main loop ----------
  for (int it = 0; it < 10; ++it) {
    if (blk < BQ) solve_body(ws, sm, blk);
    gridbar(bs);
    if (tile < 12) dzupd_body(ws, sm, G2, out, cnt, tile, b, (it == 9) ? 1 : 0);
    if (it < 9) {
      gridbar(bs);
      if (tile < 12) prep_body(ws, sm, G2, tile, b);
      sbuild_body(ws, sm, G2, tile, b);
      gridbar(bs);
    }
  }
}

extern "C" void kernel_launch(void* const* d_in, const int* in_sizes, int n_in,
                              void* d_out, int out_size, void* d_ws, size_t ws_size,
                              hipStream_t stream) {
  const float* puzzles = (const float*)d_in[0];
  const float* G2      = (const float*)d_in[1];
  const float* z2      = (const float*)d_in[2];
  const float* s2      = (const float*)d_in[3];
  float* out = (float*)d_out;
  double* ws = (double*)d_ws;

  (void)hipFuncSetAttribute(reinterpret_cast<const void*>(&persist_kernel),
                            hipFuncAttributeMaxDynamicSharedMemorySize, SMEM_BYTES);
  // zero barrier + per-batch counters (ws re-poisoned 0xAA before each launch)
  (void)hipMemsetAsync((char*)d_ws + (size_t)OFF_BARD * 8, 0, 1280, stream);

  // 142 KB LDS/block -> exactly 1 block/CU, grid == 256 CUs: all co-resident.
  persist_kernel<<<dim3(NBLK), dim3(NTHR), SMEM_BYTES, stream>>>(puzzles, G2, z2, s2, ws, out);
}

// Round 9
// 1233.063 us; speedup vs baseline: 2.8160x; 2.0373x over previous
//
#include <hip/hip_runtime.h>
#include <math.h>

#define NXQ 729
#define M2Q 128
#define MQ  857
#define BQ  16
#define QPEN_ 0.1
#define SIGMA_ 0.1

typedef double d4 __attribute__((ext_vector_type(4)));

// workspace offsets (in doubles)
constexpr int OFF_P    = 0;                        // 16x729
constexpr int OFF_H2   = OFF_P + BQ*NXQ;           // 128
constexpr int OFF_Z    = OFF_H2 + M2Q;             // 16x729
constexpr int OFF_S    = OFF_Z + BQ*NXQ;           // 16x857
constexpr int OFF_LAM  = OFF_S + BQ*MQ;            // 16x857
constexpr int OFF_D    = OFF_LAM + BQ*MQ;          // 16x857
constexpr int OFF_RP   = OFF_D + BQ*MQ;            // 16x857
constexpr int OFF_V    = OFF_RP + BQ*MQ;           // 16x857
constexpr int OFF_AINV = OFF_V + BQ*MQ;            // 16x729
constexpr int OFF_Y    = OFF_AINV + BQ*NXQ;        // 16x729
constexpr int OFF_GZ2  = OFF_Y + BQ*NXQ;           // 16x128
constexpr int OFF_Q2   = OFF_GZ2 + BQ*M2Q;         // 16x128
constexpr int OFF_USOL = OFF_Q2 + BQ*M2Q;          // 16x128
constexpr int OFF_G2B  = OFF_USOL + BQ*M2Q;        // 16x128
constexpr int OFF_TP   = OFF_G2B + BQ*M2Q;         // 12x16x128 t partials
constexpr int OFF_CMIN = OFF_TP + 12*BQ*M2Q;       // 13x16 alpha partial mins
constexpr int OFF_SG   = OFF_CMIN + 13*BQ + 48;    // 16x128x128 S matrices
constexpr int OFF_DZS  = OFF_SG;                   // 16x768 ALIASES SG prefix
                                                   // (S consumed by solve before dzupd writes;
                                                   //  prepsbuild rewrites SG afterwards)
constexpr int OFF_CNTD = OFF_SG + BQ*M2Q*M2Q;      // per-batch counters (uints), 8 dbl

// solve LDS layout (doubles)
constexpr int L_SL   = 0;                  // 128 x 129 = 16512
constexpr int L_US   = 16512;              // 128
constexpr int L_INVD = 16640;              // 128
constexpr int L_RED2 = 16768;              // 512
constexpr int L_RED  = 17280;              // 8
constexpr int SH_SOLVE = (17288) * 8;      // 138304 B
constexpr int SH_PS    = 4 * 2176 * 8;     // 69632 B (sbuild core; prep reuses prefix)

__device__ __forceinline__ double wred_sum(double v) {
#pragma unroll
  for (int off = 32; off > 0; off >>= 1) v += __shfl_down(v, off, 64);
  return v;
}
__device__ __forceinline__ double wred_min(double v) {
#pragma unroll
  for (int off = 32; off > 0; off >>= 1) v = fmin(v, __shfl_down(v, off, 64));
  return v;
}
__device__ __forceinline__ double rsqrt64(double x) { return rsqrt(x); }

// ---------------------------------------------------------------------------
// init: grid 144 x 512. Blocks 0..15: per-batch state + first-iter elementwise
// prep (mu=1 exactly). Blocks 16..143: h2 row r + m2-row prep for all batches.
// ---------------------------------------------------------------------------
__global__ __launch_bounds__(512)
void init_kernel(const float* __restrict__ puzzles, const float* __restrict__ G2,
                 const float* __restrict__ z2in, const float* __restrict__ s2in,
                 double* __restrict__ ws) {
  const int blk = blockIdx.x;
  const int tid = threadIdx.x, wave = tid >> 6, lane = tid & 63;
  __shared__ double sm[32];
  if (blk < BQ) {
    const int bb = blk;
    for (int i = tid; i < NXQ; i += 512) {
      ws[OFF_P + bb * NXQ + i] = -(double)puzzles[bb * NXQ + i];
      ws[OFF_Z + bb * NXQ + i] = 0.0;
      ws[OFF_AINV + bb * NXQ + i] = 1.0 / (QPEN_ + 1.0);
      ws[OFF_RP + bb * MQ + i] = 1.0;       // s - z = 1
      ws[OFF_V + bb * MQ + i] = SIGMA_;     // 0.1/1 - 1 + 1*1
    }
    for (int i = tid; i < MQ; i += 512) {
      ws[OFF_S + bb * MQ + i] = 1.0;
      ws[OFF_LAM + bb * MQ + i] = 1.0;
      ws[OFF_D + bb * MQ + i] = 1.0;
    }
    if (tid < M2Q) ws[OFF_GZ2 + bb * M2Q + tid] = 0.0;
    if (tid == 0) ((unsigned*)(ws + OFF_CNTD))[bb] = 0u;
  } else {
    const int r = blk - 16;
    double acc = 0.0;
    for (int kx = tid; kx < NXQ; kx += 512)
      acc += (double)G2[r * NXQ + kx] * (double)z2in[kx];
    acc = wred_sum(acc);
    if (lane == 0) sm[wave] = acc;
    __syncthreads();
    if (tid == 0) {
      double t = 0.0;
#pragma unroll
      for (int w = 0; w < 8; ++w) t += sm[w];
      const double h2r = t + (double)s2in[r];
      ws[OFF_H2 + r] = h2r;
      sm[16] = h2r;
    }
    __syncthreads();
    if (tid < BQ) {
      const double rp2 = 1.0 - sm[16];               // gz2(0) + s(1) - h2
      ws[OFF_RP + tid * MQ + NXQ + r] = rp2;
      ws[OFF_V  + tid * MQ + NXQ + r] = rp2 - 0.9;   // 0.1 - 1 + rp2
      ws[OFF_Q2 + tid * M2Q + r] = rp2 + 0.1;        // lam + v
    }
  }
}

// ---------------------------------------------------------------------------
// prepsbuild: grid (16 tiles, 16 batches) x 512.
// tile<12: prep chunk (rhs,y + t partials). All: sbuild 32x32 tile (waves 0-3).
// ---------------------------------------------------------------------------
__global__ __launch_bounds__(512)
void ps_kernel(const float* __restrict__ G2, double* __restrict__ ws) {
  const int tile = blockIdx.x, b = blockIdx.y;
  const int tid = threadIdx.x, wave = tid >> 6, lane = tid & 63;
  extern __shared__ double sm[];

  // ---- prep chunk (R5 prep verbatim + R7 t-partials) ----
  if (tile < 12) {
    double* uvec = sm;           // 128
    double* part = sm + 128;     // 512
    double* yl   = sm + 640;     // 64
    const int c0 = tile * 64;
    if (tid < M2Q) uvec[tid] = ws[OFF_Q2 + b * M2Q + tid];
    __syncthreads();
    const int kk = tid & 63, rq = tid >> 6;
    const int k = c0 + kk;
    const int kg = (k < NXQ) ? k : (NXQ - 1);
    {
      const float* gp = G2 + (rq * 16) * NXQ + kg;
      double acc = 0.0;
#pragma unroll
      for (int j = 0; j < 16; ++j) acc = fma((double)gp[j * NXQ], uvec[rq * 16 + j], acc);
      part[rq * 64 + kk] = acc;
    }
    __syncthreads();
    if (tid < 64) {
      const int k2 = c0 + tid;
      double y = 0.0;
      if (k2 < NXQ) {
        double w = 0.0;
#pragma unroll
        for (int q = 0; q < 8; ++q) w += part[q * 64 + tid];
        const double rhsk = -(QPEN_ * ws[OFF_Z + b * NXQ + k2] + ws[OFF_P + b * NXQ + k2]
                              - ws[OFF_LAM + b * MQ + k2] - ws[OFF_V + b * MQ + k2] + w);
        y = ws[OFF_AINV + b * NXQ + k2] * rhsk;
        ws[OFF_Y + b * NXQ + k2] = y;
      }
      yl[tid] = y;
    }
    __syncthreads();
    // t partials: wave rq handles rows rq*16..rq*16+15 (yl zero-padded)
    const double yv = yl[lane];
#pragma unroll
    for (int jr = 0; jr < 16; ++jr) {
      const int r = rq * 16 + jr;
      double v = (double)G2[r * NXQ + kg] * yv;
      v = wred_sum(v);
      if (lane == 0) ws[OFF_TP + (tile * BQ + b) * M2Q + r] = v;
    }
    __syncthreads();
  }

  // ---- sbuild (R8 wave-gated core at 512 thr) ----
  const int R0 = (tile >> 2) * 32, C0 = (tile & 3) * 32;
  double* As = sm + wave * 2176;
  double* Bs = As + 1088;
  const double* __restrict__ ainv = ws + OFF_AINV + b * NXQ;
  const int k0w = wave * 183;
  const int kend = min(k0w + 183, NXQ);
  const int rg4 = (lane >> 3) * 4, cg4 = (lane & 7) * 4;
  double acc[4][4];
#pragma unroll
  for (int i = 0; i < 4; ++i)
#pragma unroll
    for (int j = 0; j < 4; ++j) acc[i][j] = 0.0;

  const int kk2 = lane & 31;
  for (int ch = 0; ch < 6; ++ch) {
    __syncthreads();
    if (wave < 4) {
      const int k = k0w + ch * 32 + kk2;
      const bool ok = (k < kend);
      const double aik = ok ? ainv[k] : 0.0;
#pragma unroll
      for (int it = 0; it < 16; ++it) {
        const int rr = (it << 1) | (lane >> 5);
        double av = 0.0, bv = 0.0;
        if (ok) {
          av = (double)G2[(R0 + rr) * NXQ + k] * aik;
          bv = (double)G2[(C0 + rr) * NXQ + k];
        }
        As[kk2 * 34 + rr] = av;
        Bs[kk2 * 34 + rr] = bv;
      }
    }
    __syncthreads();
    if (wave < 4) {
#pragma unroll 8
      for (int q = 0; q < 32; ++q) {
        const double a0 = As[q*34 + rg4 + 0], a1 = As[q*34 + rg4 + 1],
                     a2 = As[q*34 + rg4 + 2], a3 = As[q*34 + rg4 + 3];
        const double b0 = Bs[q*34 + cg4 + 0], b1 = Bs[q*34 + cg4 + 1],
                     b2 = Bs[q*34 + cg4 + 2], b3 = Bs[q*34 + cg4 + 3];
        acc[0][0] += a0*b0; acc[0][1] += a0*b1; acc[0][2] += a0*b2; acc[0][3] += a0*b3;
        acc[1][0] += a1*b0; acc[1][1] += a1*b1; acc[1][2] += a1*b2; acc[1][3] += a1*b3;
        acc[2][0] += a2*b0; acc[2][1] += a2*b1; acc[2][2] += a2*b2; acc[2][3] += a2*b3;
        acc[3][0] += a3*b0; acc[3][1] += a3*b1; acc[3][2] += a3*b2; acc[3][3] += a3*b3;
      }
    }
  }
  __syncthreads();
  if (wave < 4) {
#pragma unroll
    for (int i = 0; i < 4; ++i)
#pragma unroll
      for (int j = 0; j < 4; ++j)
        As[(rg4 + i) * 32 + cg4 + j] = acc[i][j];
  }
  __syncthreads();
  double* __restrict__ Sgb = ws + OFF_SG + b * (M2Q * M2Q);
  for (int idx = tid; idx < 1024; idx += 512) {
    const double v = sm[idx] + sm[2176 + idx] + sm[4352 + idx] + sm[6528 + idx];
    Sgb[(R0 + (idx >> 5)) * M2Q + C0 + (idx & 31)] = v;
  }
}

// ---------------------------------------------------------------------------
// solve: 16 blocks x 512. Factor K = S + D2inv, solve K u = t (t from partials).
// ---------------------------------------------------------------------------
__global__ __launch_bounds__(512, 2)
void solve_kernel(double* __restrict__ ws) {
  const int b = blockIdx.x;
  const int tid = threadIdx.x, wave = tid >> 6, lane = tid & 63;
  extern __shared__ double sm[];
  double (*Sl)[129] = (double(*)[129])(sm + L_SL);
  double* us   = sm + L_US;
  double* invd = sm + L_INVD;
  double* red2 = sm + L_RED2;
  double* red  = sm + L_RED;
  double* s_   = ws + OFF_S   + b * MQ;
  double* lam_ = ws + OFF_LAM + b * MQ;
  double* Sgb  = ws + OFF_SG  + b * M2Q * M2Q;

  {
    const double2* __restrict__ Sg2 = (const double2*)Sgb;
    for (int idx = tid; idx < M2Q * M2Q / 2; idx += 512) {
      const double2 v = Sg2[idx];
      const int r = idx >> 6, c = (idx & 63) * 2;
      Sl[r][c] = v.x; Sl[r][c + 1] = v.y;
    }
  }
  if (tid < M2Q) {
    double t = 0.0;
#pragma unroll
    for (int c = 0; c < 12; ++c) t += ws[OFF_TP + (c * BQ + b) * M2Q + tid];
    us[tid] = t;
  }
  __syncthreads();
  if (tid < M2Q) Sl[tid][tid] += s_[NXQ + tid] / lam_[NXQ + tid];
  __syncthreads();

  // runtime probe of f64 MFMA C/D register->(row,col) mapping (verified R4)
  int rowm[4], colm[4];
  {
    const int rc = lane & 15, kq = lane >> 4;
    const double avr = (kq == 0) ? (double)rc : 0.0;
    const double bv1 = (kq == 0) ? 1.0 : 0.0;
    const double av1 = (kq == 0) ? 1.0 : 0.0;
    const double bvc = (kq == 0) ? (double)rc : 0.0;
    d4 zero = {0.0, 0.0, 0.0, 0.0};
    d4 dr = __builtin_amdgcn_mfma_f64_16x16x4f64(avr, bv1, zero, 0, 0, 0);
    d4 dc = __builtin_amdgcn_mfma_f64_16x16x4f64(av1, bvc, zero, 0, 0, 0);
#pragma unroll
    for (int e = 0; e < 4; ++e) { rowm[e] = (int)dr[e]; colm[e] = (int)dc[e]; }
  }

  // blocked Cholesky (NB=16) with forward substitution as extra TRSM row
  for (int kb = 0; kb < 8; ++kb) {
    const int K0 = kb * 16, J0 = K0 + 16, T = 128 - J0;
    if (wave == 0 && lane < 16) {
      const int r = lane;
      double a[16];
#pragma unroll
      for (int c = 0; c < 16; ++c) a[c] = Sl[K0 + r][K0 + c];
#pragma unroll
      for (int c = 0; c < 16; ++c) {
        const double dcc = __shfl(a[c], c, 64);
        const double rs = rsqrt64(dcc);
        a[c] *= rs;
        if (lane == c) invd[K0 + c] = rs;
#pragma unroll
        for (int k2 = c + 1; k2 < 16; ++k2) {
          const double lkc = __shfl(a[c], k2, 64);
          a[k2] = fma(-a[c], lkc, a[k2]);
        }
      }
#pragma unroll
      for (int c = 0; c < 16; ++c) Sl[K0 + r][K0 + c] = a[c];
    }
    __syncthreads();

    if (tid <= T) {
      const bool isU = (tid == T);
      double l[16];
      if (isU) {
#pragma unroll
        for (int c = 0; c < 16; ++c) l[c] = us[K0 + c];
      } else {
#pragma unroll
        for (int c = 0; c < 16; ++c) l[c] = Sl[J0 + tid][K0 + c];
      }
#pragma unroll
      for (int c = 0; c < 16; ++c) {
        const double lc = l[c] * invd[K0 + c];
        l[c] = lc;
#pragma unroll
        for (int k2 = c + 1; k2 < 16; ++k2)
          l[k2] = fma(-lc, Sl[K0 + k2][K0 + c], l[k2]);
      }
      if (isU) {
#pragma unroll
        for (int c = 0; c < 16; ++c) us[K0 + c] = l[c];
      } else {
#pragma unroll
        for (int c = 0; c < 16; ++c) Sl[J0 + tid][K0 + c] = l[c];
      }
    }
    __syncthreads();

    if (kb < 7) {
      if (tid < T) {
        double acc = 0.0;
#pragma unroll
        for (int c = 0; c < 16; ++c) acc = fma(Sl[J0 + tid][K0 + c], us[K0 + c], acc);
        us[J0 + tid] -= acc;
      }
      const int Tb = 7 - kb;
      const int rc = lane & 15, kq = lane >> 4;
      for (int idx = wave; idx < Tb * Tb; idx += 8) {
        const int i0 = J0 + (idx / Tb) * 16;
        const int j0 = J0 + (idx % Tb) * 16;
        d4 acc;
#pragma unroll
        for (int e = 0; e < 4; ++e) acc[e] = Sl[i0 + rowm[e]][j0 + colm[e]];
#pragma unroll
        for (int m = 0; m < 4; ++m) {
          const double av = -Sl[i0 + rc][K0 + 4 * m + kq];
          const double bv =  Sl[j0 + rc][K0 + 4 * m + kq];
          acc = __builtin_amdgcn_mfma_f64_16x16x4f64(av, bv, acc, 0, 0, 0);
        }
#pragma unroll
        for (int e = 0; e < 4; ++e) Sl[i0 + rowm[e]][j0 + colm[e]] = acc[e];
      }
    }
    __syncthreads();
  }

  // backward substitution L^T u = u'
  for (int kb = 7; kb >= 0; --kb) {
    const int K0 = kb * 16;
    if (kb < 7) {
      const int c = tid & 15, ch = tid >> 4;  // ch 0..31
      double part = 0.0;
      for (int k = K0 + 16 + ch; k < 128; k += 32) part = fma(Sl[k][K0 + c], us[k], part);
      red2[c * 32 + ch] = part;
      __syncthreads();
      if (tid < 16) {
        double acc = 0.0;
#pragma unroll
        for (int q = 0; q < 32; ++q) acc += red2[tid * 32 + q];
        us[K0 + tid] -= acc;
      }
      __syncthreads();
    }
    if (wave == 0 && lane < 16) {
      const int j = lane;
      double colv[16];
#pragma unroll
      for (int c = 0; c < 16; ++c) colv[c] = Sl[K0 + c][K0 + j];
      double x = us[K0 + j];
      const double iv = invd[K0 + j];
#pragma unroll
      for (int cc = 0; cc < 16; ++cc) {
        const int c = 15 - cc;
        const double xiv = x * iv;
        const double uc = __shfl(xiv, c, 64);
        if (j == c) x = xiv;
        else if (j < c) x = fma(-colv[c], uc, x);
      }
      us[K0 + j] = x;
    }
    __syncthreads();
  }

  // tail: write u, g2b = D2inv*u; m2-part ratio min -> cmin slot 12
  double lmin = 1e300;
  if (tid < M2Q) {
    const double u = us[tid];
    ws[OFF_USOL + b * M2Q + tid] = u;
    const double g = (s_[NXQ + tid] / lam_[NXQ + tid]) * u;
    ws[OFF_G2B + b * M2Q + tid] = g;
    const int i = NXQ + tid;
    const double dsi = -ws[OFF_RP + b * MQ + i] - g;
    const double dlami = ws[OFF_V + b * MQ + i] + ws[OFF_D + b * MQ + i] * g;
    if (dsi < 0.0)   lmin = fmin(lmin, -s_[i] / dsi);
    if (dlami < 0.0) lmin = fmin(lmin, -lam_[i] / dlami);
  }
  if (tid < 128) {
    lmin = wred_min(lmin);
    if (lane == 0) red[wave] = lmin;
  }
  __syncthreads();
  if (tid == 0) ws[OFF_CMIN + 12 * BQ + b] = fmin(red[0], red[1]);
}

// ---------------------------------------------------------------------------
// dzupd: grid (12 chunks, 16 batches) x 512. dz chunk matvec + ratio min;
// 12th-arriving block per batch runs the fused update + elementwise prep.
// ---------------------------------------------------------------------------
__global__ __launch_bounds__(512)
void dzupd_kernel(const float* __restrict__ G2, double* __restrict__ ws,
                  float* __restrict__ out, const int last) {
  const int chunk = blockIdx.x, b = blockIdx.y;
  const int tid = threadIdx.x, lane = tid & 63, wave = tid >> 6;
  __shared__ double uvec[128];
  __shared__ double part[512];
  __shared__ double red[8];
  __shared__ double sc2[2];
  __shared__ int updflag;
  unsigned* cnt = (unsigned*)(ws + OFF_CNTD);
  const int c0 = chunk * 64;
  if (tid < M2Q) uvec[tid] = ws[OFF_USOL + b * M2Q + tid];
  __syncthreads();
  const int kk = tid & 63, rq = tid >> 6;
  const int k = c0 + kk;
  const int kg = (k < NXQ) ? k : (NXQ - 1);
  {
    const float* gp = G2 + (rq * 16) * NXQ + kg;
    double acc = 0.0;
#pragma unroll
    for (int j = 0; j < 16; ++j) acc = fma((double)gp[j * NXQ], uvec[rq * 16 + j], acc);
    part[rq * 64 + kk] = acc;
  }
  __syncthreads();
  double lmin = 1e300;
  if (tid < 64) {
    const int k2 = c0 + tid;
    if (k2 < NXQ) {
      double w = 0.0;
#pragma unroll
      for (int q = 0; q < 8; ++q) w += part[q * 64 + tid];
      const double dz = ws[OFF_Y + b * NXQ + k2] - ws[OFF_AINV + b * NXQ + k2] * w;
      ws[OFF_DZS + b * 768 + k2] = dz;
      const double dsi = dz - ws[OFF_RP + b * MQ + k2];
      const double dlami = ws[OFF_V + b * MQ + k2] - ws[OFF_D + b * MQ + k2] * dz;
      if (dsi < 0.0)   lmin = fmin(lmin, -ws[OFF_S + b * MQ + k2] / dsi);
      if (dlami < 0.0) lmin = fmin(lmin, -ws[OFF_LAM + b * MQ + k2] / dlami);
    }
    lmin = wred_min(lmin);
    if (tid == 0) ws[OFF_CMIN + chunk * BQ + b] = lmin;
  }
  __syncthreads();
  if (tid == 0) {
    __threadfence();   // release own dzs/cmin writes
    const unsigned prev = __hip_atomic_fetch_add(&cnt[b], 1u, __ATOMIC_ACQ_REL, __HIP_MEMORY_SCOPE_AGENT);
    updflag = (prev == 11u) ? 1 : 0;
    if (updflag) __threadfence();   // acquire peers' dzs/cmin
  }
  __syncthreads();
  if (!updflag) return;

  // ---- inline update for batch b (R5 upd_kernel body) ----
  double* z    = ws + OFF_Z   + b * NXQ;
  double* s_   = ws + OFF_S   + b * MQ;
  double* lam_ = ws + OFF_LAM + b * MQ;
  double* dd   = ws + OFF_D   + b * MQ;
  double* rp   = ws + OFF_RP  + b * MQ;
  double* vv   = ws + OFF_V   + b * MQ;
  double* gz2  = ws + OFF_GZ2 + b * M2Q;
  if (tid == 0) {
    double m = 1e300;
#pragma unroll
    for (int c = 0; c < 13; ++c) m = fmin(m, ws[OFF_CMIN + c * BQ + b]);
    sc2[0] = fmin(1.0, 0.99 * m);
    __hip_atomic_store(&cnt[b], 0u, __ATOMIC_RELAXED, __HIP_MEMORY_SCOPE_AGENT);
  }
  __syncthreads();
  const double alpha = sc2[0];
  for (int i = tid; i < NXQ; i += 512) {
    const double dz = ws[OFF_DZS + b * 768 + i];
    s_[i]   += alpha * (dz - rp[i]);
    lam_[i] += alpha * (vv[i] - dd[i] * dz);
    const double zi = z[i] + alpha * dz;
    z[i] = zi;
    out[b * NXQ + i] = (float)zi;
  }
  if (tid < M2Q) {
    const int i = NXQ + tid;
    const double g = ws[OFF_G2B + b * M2Q + tid];
    s_[i]   += alpha * (-rp[i] - g);
    lam_[i] += alpha * (vv[i] + dd[i] * g);
    gz2[tid] += alpha * g;
  }
  __syncthreads();
  if (last) return;

  double musum = 0.0;
  for (int i = tid; i < MQ; i += 512) {
    const double si = s_[i], li = lam_[i];
    dd[i] = li / si;
    const double rpi = (i < NXQ) ? (si - z[i]) : (gz2[i - NXQ] + si - ws[OFF_H2 + i - NXQ]);
    rp[i] = rpi;
    musum += si * li;
  }
  musum = wred_sum(musum);
  if (lane == 0) red[wave] = musum;
  __syncthreads();
  if (tid == 0) {
    double t = 0.0;
#pragma unroll
    for (int w = 0; w < 8; ++w) t += red[w];
    sc2[1] = SIGMA_ * (t / (double)MQ);
  }
  __syncthreads();
  const double smu = sc2[1];
  for (int i = tid; i < MQ; i += 512) {
    const double si = s_[i], li = lam_[i];
    const double vi = smu / si - li + dd[i] * rp[i];
    vv[i] = vi;
    if (i >= NXQ) ws[OFF_Q2 + b * M2Q + (i - NXQ)] = li + vi;
    else ws[OFF_AINV + b * NXQ + i] = 1.0 / (QPEN_ + dd[i]);
  }
}

extern "C" void kernel_launch(void* const* d_in, const int* in_sizes, int n_in,
                              void* d_out, int out_size, void* d_ws, size_t ws_size,
                              hipStream_t stream) {
  const float* puzzles = (const float*)d_in[0];
  const float* G2      = (const float*)d_in[1];
  const float* z2      = (const float*)d_in[2];
  const float* s2      = (const float*)d_in[3];
  float* out = (float*)d_out;
  double* ws = (double*)d_ws;

  (void)hipFuncSetAttribute(reinterpret_cast<const void*>(&solve_kernel),
                            hipFuncAttributeMaxDynamicSharedMemorySize, SH_SOLVE);
  (void)hipFuncSetAttribute(reinterpret_cast<const void*>(&ps_kernel),
                            hipFuncAttributeMaxDynamicSharedMemorySize, SH_PS);

  init_kernel<<<dim3(16 + M2Q), dim3(512), 0, stream>>>(puzzles, G2, z2, s2, ws);
  ps_kernel<<<dim3(16, BQ), dim3(512), SH_PS, stream>>>(G2, ws);
  for (int it = 0; it < 10; ++it) {
    solve_kernel<<<dim3(BQ), dim3(512), SH_SOLVE, stream>>>(ws);
    dzupd_kernel<<<dim3(12, BQ), dim3(512), 0, stream>>>(G2, ws, out, (it == 9) ? 1 : 0);
    if (it < 9)
      ps_kernel<<<dim3(16, BQ), dim3(512), SH_PS, stream>>>(G2, ws);
  }
}